// Round 6
// baseline (424.740 us; speedup 1.0000x reference)
//
#include <hip/hip_runtime.h>
#include <cstdint>
#include <cstddef>

// GCN: N=512, B=64, F=O=128, E=3, 2 layers. fp32 in memory, bf16 MFMA compute.
//
//   k_prep    : 8 blocks; weights -> wt bf16 [layer][4][o][f] (g<3: W[e]^T, 3: Wh^T)
//   k_support : grid (8,64); sup[e,b,o,n] = bf16(W^T X^T + bias), tg = sigmoid(X Wh + bh)
//   k_agg<L>  : grid (16,64) = (m-tile 32, b); out = relu(sum_e adj.sup^T)*t + x*(1-t)
//               Double-buffered LDS, prefetch chunk ch+1 BEFORE computing ch,
//               ONE barrier/iter. XOR-swizzled 16B chunks (pos = c ^ (row&7)),
//               unpadded LDS (global_load_lds-compatible), free 2-way banks.
//               L=1: A = fp32 adj (reg prefetch + cvt), also writes adjb bf16.
//               L=2: A = adjb via global_load_lds (L3-resident).
// Layer-1 h lives in d_out; layer 2 in-place on d_out.

typedef __bf16 bf16x8 __attribute__((ext_vector_type(8)));
typedef float f32x4 __attribute__((ext_vector_type(4)));
typedef unsigned short u16x8 __attribute__((ext_vector_type(8)));

#define MFMA16(a, b, c) __builtin_amdgcn_mfma_f32_16x16x32_bf16((a), (b), (c), 0, 0, 0)

__device__ __forceinline__ unsigned short f2bf(float f) {  // RNE
  union { float f; unsigned int i; } v;
  v.f = f;
  return (unsigned short)((v.i + 0x7FFFu + ((v.i >> 16) & 1u)) >> 16);
}

__device__ __forceinline__ u16x8 cvt8(float4 v0, float4 v1) {
  return (u16x8){ f2bf(v0.x), f2bf(v0.y), f2bf(v0.z), f2bf(v0.w),
                  f2bf(v1.x), f2bf(v1.y), f2bf(v1.z), f2bf(v1.w) };
}

__device__ __forceinline__ void gl_lds16(const void* g, void* l) {
  __builtin_amdgcn_global_load_lds(
      (__attribute__((address_space(1))) void*)(g),
      (__attribute__((address_space(3))) void*)(l), 16, 0, 0);
}

// ---------------------------------------------------------------------------
// k_prep: 8 blocks; each transposes one 128x128 weight fp32 -> bf16 [o][f].
// ---------------------------------------------------------------------------
__global__ __launch_bounds__(256) void k_prep(
    const float* __restrict__ W1, const float* __restrict__ Wh1,
    const float* __restrict__ W2, const float* __restrict__ Wh2,
    unsigned short* __restrict__ wt) {
  __shared__ unsigned short T[128 * 136];
  const int tid = threadIdx.x;
  const int layer = blockIdx.x >> 2, g = blockIdx.x & 3;
  const float* src = (g < 3) ? ((layer ? W2 : W1) + g * 16384)
                             : (layer ? Wh2 : Wh1);
  unsigned short* dst = wt + layer * 65536 + g * 16384;
#pragma unroll
  for (int i = 0; i < 16; ++i) {
    int c = i * 256 + tid, f = c >> 5, p = (c & 31) * 4;
    float4 v = *(const float4*)(src + f * 128 + p);
    T[(p + 0) * 136 + f] = f2bf(v.x);
    T[(p + 1) * 136 + f] = f2bf(v.y);
    T[(p + 2) * 136 + f] = f2bf(v.z);
    T[(p + 3) * 136 + f] = f2bf(v.w);
  }
  __syncthreads();
#pragma unroll
  for (int i = 0; i < 8; ++i) {
    int c = i * 256 + tid, o = c >> 4, p = (c & 15) * 8;
    *(uint4*)(dst + o * 128 + p) = *(const uint4*)(&T[o * 136 + p]);
  }
}

// ---------------------------------------------------------------------------
// k_support: grid (8,64) = (n-tile 64, b). 4 waves.
// g<3 : D[o,n] = W[g]^T @ X^T -> sup bf16 (+bias)     (M=o 128, N=n 64)
// g==3: D[n,o] = X @ Wh       -> tg fp32 sigmoid
// ---------------------------------------------------------------------------
__global__ __launch_bounds__(256) void k_support(
    const float* __restrict__ x, const unsigned short* __restrict__ wt,
    const float* __restrict__ bias, const float* __restrict__ bh,
    unsigned short* __restrict__ sup, float* __restrict__ tg) {
  __shared__ __align__(16) unsigned short Xs[64 * 136];
  __shared__ __align__(16) unsigned short Ws[128 * 136];
  const int tid = threadIdx.x, lane = tid & 63, wv = tid >> 6;
  const int l15 = lane & 15, q = lane >> 4;
  const int b = blockIdx.y, n0 = blockIdx.x * 64;

#pragma unroll
  for (int is = 0; is < 8; ++is) {
    int flat = is * 256 + tid;
    int row = flat >> 5, c4 = (flat & 31) * 4;
    float4 v = *(const float4*)(x + (size_t)(n0 + row) * 8192 + b * 128 + c4);
    ushort4 u = { f2bf(v.x), f2bf(v.y), f2bf(v.z), f2bf(v.w) };
    *(ushort4*)(&Xs[row * 136 + c4]) = u;
  }

  for (int g = 0; g < 4; ++g) {
    __syncthreads();
#pragma unroll
    for (int is = 0; is < 8; ++is) {
      int flat = is * 256 + tid;
      int row = flat >> 4, c8 = (flat & 15) * 8;
      *(uint4*)(&Ws[row * 136 + c8]) =
          *(const uint4*)(wt + g * 16384 + row * 128 + c8);
    }
    __syncthreads();

    if (g < 3) {
      f32x4 acc[4][2];
#pragma unroll
      for (int i = 0; i < 4; ++i)
#pragma unroll
        for (int j = 0; j < 2; ++j) acc[i][j] = (f32x4){0.f, 0.f, 0.f, 0.f};
#pragma unroll
      for (int kt = 0; kt < 4; ++kt) {
        int kf = kt * 32 + q * 8;
        bf16x8 a[4], bb[2];
#pragma unroll
        for (int mt = 0; mt < 4; ++mt)
          a[mt] = *(const bf16x8*)(&Ws[((wv >> 1) * 64 + mt * 16 + l15) * 136 + kf]);
#pragma unroll
        for (int nt = 0; nt < 2; ++nt)
          bb[nt] = *(const bf16x8*)(&Xs[((wv & 1) * 32 + nt * 16 + l15) * 136 + kf]);
#pragma unroll
        for (int mt = 0; mt < 4; ++mt)
#pragma unroll
          for (int nt = 0; nt < 2; ++nt)
            acc[mt][nt] = MFMA16(a[mt], bb[nt], acc[mt][nt]);
      }
      const size_t sb = (size_t)(g * 64 + b) * 65536;
#pragma unroll
      for (int mt = 0; mt < 4; ++mt) {
#pragma unroll
        for (int nt = 0; nt < 2; ++nt) {
          int nn = n0 + (wv & 1) * 32 + nt * 16 + l15;
#pragma unroll
          for (int r = 0; r < 4; ++r) {
            int o = (wv >> 1) * 64 + mt * 16 + q * 4 + r;
            float v = acc[mt][nt][r] + bias[g * 128 + o];
            sup[sb + (size_t)o * 512 + nn] = f2bf(v);
          }
        }
      }
    } else {
      f32x4 acc[2][4];
#pragma unroll
      for (int i = 0; i < 2; ++i)
#pragma unroll
        for (int j = 0; j < 4; ++j) acc[i][j] = (f32x4){0.f, 0.f, 0.f, 0.f};
#pragma unroll
      for (int kt = 0; kt < 4; ++kt) {
        int kf = kt * 32 + q * 8;
        bf16x8 a[2], bb[4];
#pragma unroll
        for (int mt = 0; mt < 2; ++mt)
          a[mt] = *(const bf16x8*)(&Xs[((wv >> 1) * 32 + mt * 16 + l15) * 136 + kf]);
#pragma unroll
        for (int nt = 0; nt < 4; ++nt)
          bb[nt] = *(const bf16x8*)(&Ws[((wv & 1) * 64 + nt * 16 + l15) * 136 + kf]);
#pragma unroll
        for (int mt = 0; mt < 2; ++mt)
#pragma unroll
          for (int nt = 0; nt < 4; ++nt)
            acc[mt][nt] = MFMA16(a[mt], bb[nt], acc[mt][nt]);
      }
#pragma unroll
      for (int mt = 0; mt < 2; ++mt) {
#pragma unroll
        for (int nt = 0; nt < 4; ++nt) {
          int o = (wv & 1) * 64 + nt * 16 + l15;
#pragma unroll
          for (int r = 0; r < 4; ++r) {
            int nn = n0 + (wv >> 1) * 32 + mt * 16 + q * 4 + r;
            float v = acc[mt][nt][r] + bh[o];
            tg[((size_t)nn * 64 + b) * 128 + o] = 1.f / (1.f + __expf(-v));
          }
        }
      }
    }
  }
}

// ---------------------------------------------------------------------------
// k_agg<LAYER>: grid (16,64) = (m-tile 32, b). 4 waves: wm=wv>>1 (m 16-group),
// wn=wv&1 (o 64-half); 4 acc frags/wave. K = 3e*512n in 24 chunks of 64.
// LDS: As 2x4KB + Bs 2x16KB = 40KB -> 4 blocks/CU. Prefetch ch+1 before
// computing ch; one barrier per iteration.
// ---------------------------------------------------------------------------
template <int LAYER>
__global__ __launch_bounds__(256) void k_agg(
    const float* __restrict__ adjf, unsigned short* __restrict__ adjb,
    const unsigned short* __restrict__ sup, const float* __restrict__ tg,
    const float* __restrict__ x, float* __restrict__ dst) {
  __shared__ __align__(16) unsigned short As[2][32 * 64];
  __shared__ __align__(16) unsigned short Bs[2][128 * 64];
  const int tid = threadIdx.x, lane = tid & 63, wv = tid >> 6;
  const int l15 = lane & 15, q = lane >> 4;
  const int wm = wv >> 1, wn = wv & 1;
  const int b = blockIdx.y, m0 = blockIdx.x * 32;
  const int arow = tid >> 3, ac8 = tid & 7;       // layer1 A staging coords
  const int grow = lane >> 3, gc8 = lane & 7;     // gl_lds lane coords

  f32x4 acc[4];
#pragma unroll
  for (int i = 0; i < 4; ++i) acc[i] = (f32x4){0.f, 0.f, 0.f, 0.f};

  float4 pv0, pv1;          // layer1 A prefetch regs
  size_t pgi = 0;

  // ---- helpers (macros to keep gl_lds dest wave-uniform) ----
#define ISSUE_B(ch, buf)                                                      \
  {                                                                           \
    int e_ = (ch) >> 3, kt_ = (ch) & 7;                                       \
    size_t sb_ = (size_t)(e_ * 64 + b) * 65536 + kt_ * 64;                    \
    _Pragma("unroll") for (int is_ = 0; is_ < 4; ++is_) {                     \
      int r_ = wv * 32 + is_ * 8 + grow;                                      \
      int gc_ = gc8 ^ (r_ & 7);                                               \
      gl_lds16(sup + sb_ + (size_t)r_ * 512 + gc_ * 8,                        \
               &Bs[buf][wv * 2048 + is_ * 512]);                              \
    }                                                                         \
  }
#define ISSUE_A2(ch, buf)                                                     \
  {                                                                           \
    int e_ = (ch) >> 3, kt_ = (ch) & 7;                                       \
    size_t ab_ = ((size_t)(e_ * 64 + b) * 512 + m0) * 512 + kt_ * 64;         \
    int r_ = wv * 8 + grow;                                                   \
    int gc_ = gc8 ^ (r_ & 7);                                                 \
    gl_lds16(adjb + ab_ + (size_t)r_ * 512 + gc_ * 8, &As[buf][wv * 512]);    \
  }
#define LOAD_A1(ch)                                                           \
  {                                                                           \
    int e_ = (ch) >> 3, kt_ = (ch) & 7;                                       \
    pgi = ((size_t)(e_ * 64 + b) * 512 + m0 + arow) * 512 + kt_ * 64 + ac8 * 8; \
    pv0 = *(const float4*)(adjf + pgi);                                       \
    pv1 = *(const float4*)(adjf + pgi + 4);                                   \
  }
#define STORE_A1(buf)                                                         \
  {                                                                           \
    u16x8 u_ = cvt8(pv0, pv1);                                                \
    *(u16x8*)(adjb + pgi) = u_;                                               \
    int p_ = ac8 ^ (arow & 7);                                                \
    *(u16x8*)(&As[buf][arow * 64 + p_ * 8]) = u_;                             \
  }

  // preload chunk 0 into buffer 0
  if (LAYER == 1) {
    LOAD_A1(0);
    STORE_A1(0);
  } else {
    ISSUE_A2(0, 0);
  }
  ISSUE_B(0, 0);
  __syncthreads();

  int cur = 0;
  for (int ch = 0; ch < 24; ++ch) {
    // issue next-chunk loads first (overlap with MFMAs below)
    if (ch + 1 < 24) {
      if (LAYER == 1) {
        LOAD_A1(ch + 1);
      } else {
        ISSUE_A2(ch + 1, cur ^ 1);
      }
      ISSUE_B(ch + 1, cur ^ 1);
    }
    // compute current chunk
#pragma unroll
    for (int kh = 0; kh < 2; ++kh) {
      int r = wm * 16 + l15;
      int pa = (kh * 4 + q) ^ (r & 7);
      bf16x8 a = *(const bf16x8*)(&As[cur][r * 64 + pa * 8]);
#pragma unroll
      for (int ot = 0; ot < 4; ++ot) {
        int ro = wn * 64 + ot * 16 + l15;
        int pb = (kh * 4 + q) ^ (ro & 7);
        bf16x8 bb = *(const bf16x8*)(&Bs[cur][ro * 64 + pb * 8]);
        acc[ot] = MFMA16(a, bb, acc[ot]);
      }
    }
    if (ch + 1 < 24) {
      if (LAYER == 1) STORE_A1(cur ^ 1);
      __syncthreads();  // drains vmcnt (gl_lds) + lgkm; flips buffer
      cur ^= 1;
    }
  }

  // Epilogue: relu + highway. C row=m (q*4+r), col=o (l15).
#pragma unroll
  for (int ot = 0; ot < 4; ++ot) {
#pragma unroll
    for (int r = 0; r < 4; ++r) {
      int m = m0 + wm * 16 + q * 4 + r;
      int o = wn * 64 + ot * 16 + l15;
      size_t ridx = (size_t)(m * 64 + b) * 128 + o;
      float agg = acc[ot][r];
      agg = agg > 0.f ? agg : 0.f;
      float tv = tg[ridx];
      float xv = x[ridx];
      dst[ridx] = fmaf(agg, tv, xv * (1.f - tv));
    }
  }
#undef ISSUE_B
#undef ISSUE_A2
#undef LOAD_A1
#undef STORE_A1
}

// ---------------------------------------------------------------------------
extern "C" void kernel_launch(void* const* d_in, const int* in_sizes, int n_in,
                              void* d_out, int out_size, void* d_ws, size_t ws_size,
                              hipStream_t stream) {
  const float* x   = (const float*)d_in[0];
  const float* adj = (const float*)d_in[1];
  const float* W1  = (const float*)d_in[2];
  const float* b1  = (const float*)d_in[3];
  const float* Wh1 = (const float*)d_in[4];
  const float* bh1 = (const float*)d_in[5];
  const float* W2  = (const float*)d_in[6];
  const float* b2  = (const float*)d_in[7];
  const float* Wh2 = (const float*)d_in[8];
  const float* bh2 = (const float*)d_in[9];
  float* out = (float*)d_out;

  char* ws = (char*)d_ws;
  unsigned short* adjb = (unsigned short*)ws;                // 100,663,296 B
  unsigned short* sup  = (unsigned short*)(ws + 100663296);  //  25,165,824 B
  float*          tg   = (float*)(ws + 125829120);           //  16,777,216 B
  unsigned short* wt   = (unsigned short*)(ws + 142606336);  //     262,144 B

  dim3 blk(256);

  k_prep<<<dim3(8), blk, 0, stream>>>(W1, Wh1, W2, Wh2, wt);

  // Layer 1 (h -> d_out); k_agg<1> also emits adjb (bf16 adj) for layer 2
  k_support<<<dim3(8, 64), blk, 0, stream>>>(x, wt, b1, bh1, sup, tg);
  k_agg<1><<<dim3(16, 64), blk, 0, stream>>>(adj, adjb, sup, tg, x, out);

  // Layer 2 (in-place on d_out)
  k_support<<<dim3(8, 64), blk, 0, stream>>>(out, wt + 65536, b2, bh2, sup, tg);
  k_agg<2><<<dim3(16, 64), blk, 0, stream>>>(adj, adjb, sup, tg, out, out);
}